// Round 5
// baseline (474.052 us; speedup 1.0000x reference)
//
#include <hip/hip_runtime.h>

#define NB 32
#define NF 256
#define NT 4096
#define PAD_LEN 256

#define TF 16
#define TT 128

// f32 gaussian weights: exp(-0.5*c^2)/sum, c=-2..2, sigma=1
#define G0 0.054488684f
#define G1 0.24420134f
#define G2 0.40261995f

// All LDS arrays share column indexing: slot s <-> global col t0-4+s, s in [0,136)
// Row stride 136 floats (544B, 16B-aligned rows).
#define SW 136
#define SW4 34
#define RS 24   // sS rows: global f0-4 .. f0+19
#define RP 22   // sP rows: global f0-3 .. f0+18
#define RV 18   // sV/sB rows: global f0-1 .. f0+16

#define R1_WORDS (RS * SW)  // sS, overlaid by sV
#define R2_WORDS (RP * SW)  // sP, overlaid by sB

__device__ __forceinline__ int reflectF(int i) {
    i = (i < 0) ? -i : i;
    return (i >= NF) ? (2 * NF - 2 - i) : i;
}
__device__ __forceinline__ int reflectT(int i) {
    i = (i < 0) ? -i : i;
    return (i >= NT) ? (2 * NT - 2 - i) : i;
}
// order-preserving float->uint encoding for atomicMin/Max
__device__ __forceinline__ unsigned encf(float x) {
    unsigned u = __float_as_uint(x);
    return (u & 0x80000000u) ? ~u : (u | 0x80000000u);
}
__device__ __forceinline__ float decf(unsigned e) {
    unsigned u = (e & 0x80000000u) ? (e ^ 0x80000000u) : ~e;
    return __uint_as_float(u);
}

// ws layout: mm[NB][4] @0 ; counts2[NB][NF][32] @1024 ; prefix2 @1024+1MB
#define MM_OFF 0
#define CNT_OFF 1024
#define PFX_OFF (1024 + NB * NF * 32 * 4)

__global__ __launch_bounds__(256) void k_init(float* __restrict__ out, unsigned* __restrict__ mm) {
    int tid = blockIdx.x * 256 + threadIdx.x;
    if (tid < NB * 3 * PAD_LEN) out[tid] = 0.0f;
    if (tid < NB) {
        mm[tid * 4 + 0] = 0xFFFFFFFFu;
        mm[tid * 4 + 1] = 0u;
        mm[tid * 4 + 2] = 0xFFFFFFFFu;
        mm[tid * 4 + 3] = 0u;
    }
}

// Deep-MLP min/max: 16 independent float4 loads in flight per thread.
__global__ __launch_bounds__(256) void k_minmax(const float* __restrict__ spec, unsigned* __restrict__ mm) {
    const int b = blockIdx.y;
    const float4* q = (const float4*)(spec + (size_t)b * NF * NT) + blockIdx.x * 4096 + threadIdx.x;
    float4 v[16];
#pragma unroll
    for (int u = 0; u < 16; u++) v[u] = q[u * 256];
    float lmin = __builtin_inff(), lmax = -__builtin_inff();
#pragma unroll
    for (int u = 0; u < 16; u++) {
        lmin = fminf(lmin, fminf(fminf(v[u].x, v[u].y), fminf(v[u].z, v[u].w)));
        lmax = fmaxf(lmax, fmaxf(fmaxf(v[u].x, v[u].y), fmaxf(v[u].z, v[u].w)));
    }
    for (int off = 32; off; off >>= 1) {
        lmin = fminf(lmin, __shfl_down(lmin, off));
        lmax = fmaxf(lmax, __shfl_down(lmax, off));
    }
    __shared__ float rmn[4], rmx[4];
    int wave = threadIdx.x >> 6, lane = threadIdx.x & 63;
    if (lane == 0) { rmn[wave] = lmin; rmx[wave] = lmax; }
    __syncthreads();
    if (threadIdx.x == 0) {
        for (int w = 1; w < 4; w++) { lmin = fminf(lmin, rmn[w]); lmax = fmaxf(lmax, rmx[w]); }
        atomicMin(&mm[b * 4 + 0], encf(lmin));
        atomicMax(&mm[b * 4 + 1], encf(lmax));
    }
}

// ---------- interior (fast) tile: ILP-unrolled, paired items, MLP register staging ----------
__device__ __forceinline__ void blur_tile_fast(const float* __restrict__ sb_base,
                                               int f0, int t0, float mn, float rinv,
                                               float* sR1, float* sR2, int tid) {
    float4* sS4 = (float4*)sR1;
    float4* sP4 = (float4*)sR2;
    float4* sV4 = (float4*)sR1;  // overlays sS
    float4* sB4 = (float4*)sR2;  // overlays sP
    float* sS = sR1;
    float* sV = sR1;
    float* sB = sR2;

    // Phase A: stage spec rows f0-4..f0+19, slots 0..135 (816 float4).
    // 4 independent global loads per thread issued back-to-back (high MLP),
    // then LDS writes — no per-iteration load->store dependency.
    {
        const float4* gp = (const float4*)(sb_base + (size_t)(f0 - 4) * NT + (t0 - 4));
        const float4* ap[4];
#pragma unroll
        for (int k = 0; k < 4; k++) {
            const int i = tid + k * 256;
            const int r = i / SW4, c = i - r * SW4;
            ap[k] = gp + r * (NT / 4) + c;
        }
        const bool a3 = tid < (RS * SW4 - 768);
        float4 v0 = ap[0][0];
        float4 v1 = ap[1][0];
        float4 v2 = ap[2][0];
        float4 v3;
        if (a3) v3 = ap[3][0];
        sS4[tid] = v0;
        sS4[tid + 256] = v1;
        sS4[tid + 512] = v2;
        if (a3) sS4[tid + 768] = v3;
    }
    __syncthreads();

    // Phase B: peak(spec)*norm -> sP, row-pairs (11 pairs x 34 col-groups = 374 items)
    {
        float4 S0[2], S1[2], S2[2], S3[2];
        float lmA[2], rpA[2], lmB[2], rpB[2];
        int r0a[2], ga[2];
        bool act[2];
#pragma unroll
        for (int k = 0; k < 2; k++) {
            const int i = tid + k * 256;
            act[k] = i < 11 * SW4;
            if (act[k]) {
                const int pr = i / SW4, g = i - pr * SW4;
                const int r0 = 2 * pr;
                r0a[k] = r0; ga[k] = g;
                S0[k] = sS4[r0 * SW4 + g];
                S1[k] = sS4[(r0 + 1) * SW4 + g];
                S2[k] = sS4[(r0 + 2) * SW4 + g];
                S3[k] = sS4[(r0 + 3) * SW4 + g];
                lmA[k] = sS[(r0 + 1) * SW + 4 * g - 1];
                rpA[k] = sS[(r0 + 1) * SW + 4 * g + 4];
                lmB[k] = sS[(r0 + 2) * SW + 4 * g - 1];
                rpB[k] = sS[(r0 + 2) * SW + 4 * g + 4];
            }
        }
#pragma unroll
        for (int k = 0; k < 2; k++) {
            if (act[k]) {
                const int g = ga[k], r0 = r0a[k];
                float4 o, p;
                o.x = (S1[k].x >= lmA[k] && S1[k].x >= S1[k].y && S1[k].x >= S0[k].x && S1[k].x >= S2[k].x) ? (S1[k].x - mn) * rinv : 0.0f;
                o.y = (S1[k].y >= S1[k].x && S1[k].y >= S1[k].z && S1[k].y >= S0[k].y && S1[k].y >= S2[k].y) ? (S1[k].y - mn) * rinv : 0.0f;
                o.z = (S1[k].z >= S1[k].y && S1[k].z >= S1[k].w && S1[k].z >= S0[k].z && S1[k].z >= S2[k].z) ? (S1[k].z - mn) * rinv : 0.0f;
                o.w = (S1[k].w >= S1[k].z && S1[k].w >= rpA[k] && S1[k].w >= S0[k].w && S1[k].w >= S2[k].w) ? (S1[k].w - mn) * rinv : 0.0f;
                p.x = (S2[k].x >= lmB[k] && S2[k].x >= S2[k].y && S2[k].x >= S1[k].x && S2[k].x >= S3[k].x) ? (S2[k].x - mn) * rinv : 0.0f;
                p.y = (S2[k].y >= S2[k].x && S2[k].y >= S2[k].z && S2[k].y >= S1[k].y && S2[k].y >= S3[k].y) ? (S2[k].y - mn) * rinv : 0.0f;
                p.z = (S2[k].z >= S2[k].y && S2[k].z >= S2[k].w && S2[k].z >= S1[k].z && S2[k].z >= S3[k].z) ? (S2[k].z - mn) * rinv : 0.0f;
                p.w = (S2[k].w >= S2[k].z && S2[k].w >= rpB[k] && S2[k].w >= S1[k].w && S2[k].w >= S3[k].w) ? (S2[k].w - mn) * rinv : 0.0f;
                if (g == 0)  { o.x = 0.0f; p.x = 0.0f; }
                if (g == 33) { o.w = 0.0f; p.w = 0.0f; }
                sP4[r0 * SW4 + g] = o;
                sP4[(r0 + 1) * SW4 + g] = p;
            }
        }
    }
    __syncthreads();

    // Phase C: vertical 5-tap -> sV, row-pairs (9 pairs x 34 = 306 items)
    {
        float4 P[2][6];
        int idx[2];
        bool act[2];
#pragma unroll
        for (int k = 0; k < 2; k++) {
            const int i = tid + k * 256;
            act[k] = i < 9 * SW4;
            if (act[k]) {
                const int pv = i / SW4, g = i - pv * SW4;
                const int r0 = 2 * pv;
                idx[k] = r0 * SW4 + g;
#pragma unroll
                for (int j = 0; j < 6; j++) P[k][j] = sP4[(r0 + j) * SW4 + g];
            }
        }
#pragma unroll
        for (int k = 0; k < 2; k++) {
            if (act[k]) {
                float4 a, b;
                a.x = G0 * (P[k][0].x + P[k][4].x) + G1 * (P[k][1].x + P[k][3].x) + G2 * P[k][2].x;
                a.y = G0 * (P[k][0].y + P[k][4].y) + G1 * (P[k][1].y + P[k][3].y) + G2 * P[k][2].y;
                a.z = G0 * (P[k][0].z + P[k][4].z) + G1 * (P[k][1].z + P[k][3].z) + G2 * P[k][2].z;
                a.w = G0 * (P[k][0].w + P[k][4].w) + G1 * (P[k][1].w + P[k][3].w) + G2 * P[k][2].w;
                b.x = G0 * (P[k][1].x + P[k][5].x) + G1 * (P[k][2].x + P[k][4].x) + G2 * P[k][3].x;
                b.y = G0 * (P[k][1].y + P[k][5].y) + G1 * (P[k][2].y + P[k][4].y) + G2 * P[k][3].y;
                b.z = G0 * (P[k][1].z + P[k][5].z) + G1 * (P[k][2].z + P[k][4].z) + G2 * P[k][3].z;
                b.w = G0 * (P[k][1].w + P[k][5].w) + G1 * (P[k][2].w + P[k][4].w) + G2 * P[k][3].w;
                sV4[idx[k]] = a;
                sV4[idx[k] + SW4] = b;
            }
        }
    }
    __syncthreads();

    // Phase D: horizontal 5-tap -> sB, col-pairs (18 rows x 16 = 288 items) + 36 edges
    {
        float4 VA[2], VB[2], VC[2], VD[2];
        int od[2];
        bool act[2];
#pragma unroll
        for (int k = 0; k < 2; k++) {
            const int i = tid + k * 256;
            act[k] = i < RV * 16;
            if (act[k]) {
                const int r = i >> 4, m = i & 15;
                const int g = 1 + 2 * m;
                od[k] = r * SW4 + g;
                VA[k] = sV4[r * SW4 + g - 1];
                VB[k] = sV4[r * SW4 + g];
                VC[k] = sV4[r * SW4 + g + 1];
                VD[k] = sV4[r * SW4 + g + 2];
            }
        }
        float ev[5];
        int eidx = 0;
        const bool eact = tid < RV * 2;
        if (eact) {
            const int r = tid >> 1;
            const int s = (tid & 1) ? 132 : 3;
            eidx = r * SW + s;
#pragma unroll
            for (int j = 0; j < 5; j++) ev[j] = sV[eidx - 2 + j];
        }
#pragma unroll
        for (int k = 0; k < 2; k++) {
            if (act[k]) {
                float4 o1, o2;
                o1.x = G0 * (VA[k].z + VB[k].z) + G1 * (VA[k].w + VB[k].y) + G2 * VB[k].x;
                o1.y = G0 * (VA[k].w + VB[k].w) + G1 * (VB[k].x + VB[k].z) + G2 * VB[k].y;
                o1.z = G0 * (VB[k].x + VC[k].x) + G1 * (VB[k].y + VB[k].w) + G2 * VB[k].z;
                o1.w = G0 * (VB[k].y + VC[k].y) + G1 * (VB[k].z + VC[k].x) + G2 * VB[k].w;
                o2.x = G0 * (VB[k].z + VC[k].z) + G1 * (VB[k].w + VC[k].y) + G2 * VC[k].x;
                o2.y = G0 * (VB[k].w + VC[k].w) + G1 * (VC[k].x + VC[k].z) + G2 * VC[k].y;
                o2.z = G0 * (VC[k].x + VD[k].x) + G1 * (VC[k].y + VC[k].w) + G2 * VC[k].z;
                o2.w = G0 * (VC[k].y + VD[k].y) + G1 * (VC[k].z + VD[k].x) + G2 * VC[k].w;
                sB4[od[k]] = o1;
                sB4[od[k] + 1] = o2;
            }
        }
        if (eact) sB[eidx] = G0 * (ev[0] + ev[4]) + G1 * (ev[1] + ev[3]) + G2 * ev[2];
    }
    __syncthreads();
}

// ---------- boundary (slow) tile: guarded, reflect-indexed ----------
__device__ __forceinline__ void blur_tile_slow(const float* __restrict__ sb_base,
                                               int f0, int t0, float mn, float rinv,
                                               float* sR1, float* sR2, int tid) {
    const float NEG = -__builtin_inff();
    float* sS = sR1;
    float* sP = sR2;
    float* sV = sR1;
    float* sB = sR2;

    for (int i = tid; i < RS * SW; i += 256) {
        int r = i / SW, c = i - r * SW;
        int gf = f0 - 4 + r, gc = t0 - 4 + c;
        float v = NEG;
        if ((unsigned)gf < NF && (unsigned)gc < NT) v = sb_base[gf * NT + gc];
        sS[i] = v;
    }
    __syncthreads();

    for (int i = tid; i < RP * 134; i += 256) {
        int r = i / 134, s = 1 + (i - r * 134);
        int gf = f0 - 3 + r, gc = t0 - 4 + s;
        float v = 0.0f;
        if ((unsigned)gf < NF && (unsigned)gc < NT) {
            const float x  = sS[(r + 1) * SW + s];
            const float xl = sS[(r + 1) * SW + s - 1];
            const float xr = sS[(r + 1) * SW + s + 1];
            const float xu = sS[r * SW + s];
            const float xd = sS[(r + 2) * SW + s];
            if (x >= xl && x >= xr && x >= xu && x >= xd) v = (x - mn) * rinv;
        }
        sP[r * SW + s] = v;
    }
    __syncthreads();

    for (int i = tid; i < RV * 134; i += 256) {
        int r = i / 134, s = 1 + (i - r * 134);
        int gf = f0 - 1 + r, gc = t0 - 4 + s;
        float acc = 0.0f;
        if ((unsigned)gf < NF && (unsigned)gc < NT) {
            int rm2 = reflectF(gf - 2) - (f0 - 3);
            int rm1 = reflectF(gf - 1) - (f0 - 3);
            int rcc = gf - (f0 - 3);
            int rp1 = reflectF(gf + 1) - (f0 - 3);
            int rp2 = reflectF(gf + 2) - (f0 - 3);
            acc  = G0 * sP[rm2 * SW + s];
            acc += G1 * sP[rm1 * SW + s];
            acc += G2 * sP[rcc * SW + s];
            acc += G1 * sP[rp1 * SW + s];
            acc += G0 * sP[rp2 * SW + s];
        }
        sV[r * SW + s] = acc;
    }
    __syncthreads();

    for (int i = tid; i < RV * 130; i += 256) {
        int r = i / 130, s = 3 + (i - r * 130);
        int gf = f0 - 1 + r, gc = t0 - 4 + s;
        float acc = NEG;
        if ((unsigned)gf < NF && (unsigned)gc < NT) {
            int cm2 = reflectT(gc - 2) - (t0 - 4);
            int cm1 = reflectT(gc - 1) - (t0 - 4);
            int cp1 = reflectT(gc + 1) - (t0 - 4);
            int cp2 = reflectT(gc + 2) - (t0 - 4);
            const float* vr = sV + r * SW;
            acc  = G0 * (vr[cm2] + vr[cp2]);
            acc += G1 * (vr[cm1] + vr[cp1]);
            acc += G2 * vr[s];
        }
        sB[r * SW + s] = acc;
    }
    __syncthreads();
}

// Epilogue helper: 8-col window for row r (global f0+r), octet m (cols t0+8m..+7)
struct Win8 {
    float c[8], l[8], rr[8], u[8], d[8];
};
__device__ __forceinline__ void load_win8(const float4* sB4, int r, int m, Win8& w) {
    const int g = 1 + 2 * m;
    const float4 Cm = sB4[(r + 1) * SW4 + g - 1];
    const float4 C0 = sB4[(r + 1) * SW4 + g];
    const float4 C1 = sB4[(r + 1) * SW4 + g + 1];
    const float4 C2 = sB4[(r + 1) * SW4 + g + 2];
    const float4 U0 = sB4[r * SW4 + g];
    const float4 U1 = sB4[r * SW4 + g + 1];
    const float4 D0 = sB4[(r + 2) * SW4 + g];
    const float4 D1 = sB4[(r + 2) * SW4 + g + 1];
    w.c[0] = C0.x; w.c[1] = C0.y; w.c[2] = C0.z; w.c[3] = C0.w;
    w.c[4] = C1.x; w.c[5] = C1.y; w.c[6] = C1.z; w.c[7] = C1.w;
    w.l[0] = Cm.w; w.l[1] = C0.x; w.l[2] = C0.y; w.l[3] = C0.z;
    w.l[4] = C0.w; w.l[5] = C1.x; w.l[6] = C1.y; w.l[7] = C1.z;
    w.rr[0] = C0.y; w.rr[1] = C0.z; w.rr[2] = C0.w; w.rr[3] = C1.x;
    w.rr[4] = C1.y; w.rr[5] = C1.z; w.rr[6] = C1.w; w.rr[7] = C2.x;
    w.u[0] = U0.x; w.u[1] = U0.y; w.u[2] = U0.z; w.u[3] = U0.w;
    w.u[4] = U1.x; w.u[5] = U1.y; w.u[6] = U1.z; w.u[7] = U1.w;
    w.d[0] = D0.x; w.d[1] = D0.y; w.d[2] = D0.z; w.d[3] = D0.w;
    w.d[4] = D1.x; w.d[5] = D1.y; w.d[6] = D1.z; w.d[7] = D1.w;
}

// Main pass: blur + blur-min/max + per-(row,chunk) counts with threshold x > 0
// (valid when mn2 == 0, which holds because blur >= 0 and empty 5x5 windows exist;
//  k_fallback recounts with the true mn2 iff mn2 != 0)
__global__ __launch_bounds__(256, 4) void k_main(const float* __restrict__ spec, unsigned* __restrict__ mm,
                                                 int* __restrict__ counts2) {
    const int b = blockIdx.z;
    const int f0 = blockIdx.y * TF;
    const int t0 = blockIdx.x * TT;
    const int c0 = blockIdx.x;
    const int tid = threadIdx.x;

    __shared__ __align__(16) float sR1[R1_WORDS];
    __shared__ __align__(16) float sR2[R2_WORDS];
    const float4* sB4 = (const float4*)sR2;

    const float mn = decf(mm[b * 4 + 0]);
    const float mx = decf(mm[b * 4 + 1]);
    const float rinv = 1.0f / (mx - mn);
    const float* sb_base = spec + (size_t)b * NF * NT;

    const bool interior = (blockIdx.y >= 1 && blockIdx.y <= 14 && blockIdx.x >= 1 && blockIdx.x <= 30);
    if (interior) blur_tile_fast(sb_base, f0, t0, mn, rinv, sR1, sR2, tid);
    else          blur_tile_slow(sb_base, f0, t0, mn, rinv, sR1, sR2, tid);

    const int r = tid >> 4, m = tid & 15;
    Win8 w;
    load_win8(sB4, r, m, w);
    int cnt = 0;
    float lmin = __builtin_inff(), lmax = -__builtin_inff();
#pragma unroll
    for (int k = 0; k < 8; k++) {
        float x = w.c[k];
        lmin = fminf(lmin, x);
        lmax = fmaxf(lmax, x);
        bool pk = (x >= w.l[k]) && (x >= w.rr[k]) && (x >= w.u[k]) && (x >= w.d[k]);
        cnt += (pk && (x > 0.0f)) ? 1 : 0;
    }
    int cs = cnt;
    cs += __shfl_down(cs, 8, 16);
    cs += __shfl_down(cs, 4, 16);
    cs += __shfl_down(cs, 2, 16);
    cs += __shfl_down(cs, 1, 16);
    if (m == 0) counts2[(b * NF + f0 + r) * 32 + c0] = cs;

    for (int off = 32; off; off >>= 1) {
        lmin = fminf(lmin, __shfl_down(lmin, off));
        lmax = fmaxf(lmax, __shfl_down(lmax, off));
    }
    __shared__ float rmn[4], rmx[4];
    int wave = tid >> 6, lane = tid & 63;
    if (lane == 0) { rmn[wave] = lmin; rmx[wave] = lmax; }
    __syncthreads();
    if (tid == 0) {
        for (int w2 = 1; w2 < 4; w2++) { lmin = fminf(lmin, rmn[w2]); lmax = fmaxf(lmax, rmx[w2]); }
        atomicMin(&mm[b * 4 + 2], encf(lmin));
        atomicMax(&mm[b * 4 + 3], encf(lmax));
    }
}

// Guard pass: only does work if mn2 != 0; recounts with threshold x > mn2.
__global__ __launch_bounds__(256, 4) void k_fallback(const float* __restrict__ spec, unsigned* __restrict__ mm,
                                                     int* __restrict__ counts2) {
    const int b = blockIdx.z;
    const float mn2 = decf(mm[b * 4 + 2]);
    if (mn2 == 0.0f) return;

    const int f0 = blockIdx.y * TF;
    const int t0 = blockIdx.x * TT;
    const int c0 = blockIdx.x;
    const int tid = threadIdx.x;

    __shared__ __align__(16) float sR1[R1_WORDS];
    __shared__ __align__(16) float sR2[R2_WORDS];
    const float4* sB4 = (const float4*)sR2;

    const float mn = decf(mm[b * 4 + 0]);
    const float mx = decf(mm[b * 4 + 1]);
    const float rinv = 1.0f / (mx - mn);
    const float* sb_base = spec + (size_t)b * NF * NT;

    blur_tile_slow(sb_base, f0, t0, mn, rinv, sR1, sR2, tid);

    const int r = tid >> 4, m = tid & 15;
    Win8 w;
    load_win8(sB4, r, m, w);
    int cnt = 0;
#pragma unroll
    for (int k = 0; k < 8; k++) {
        float x = w.c[k];
        bool pk = (x >= w.l[k]) && (x >= w.rr[k]) && (x >= w.u[k]) && (x >= w.d[k]);
        cnt += (pk && (x > mn2)) ? 1 : 0;
    }
    cnt += __shfl_down(cnt, 8, 16);
    cnt += __shfl_down(cnt, 4, 16);
    cnt += __shfl_down(cnt, 2, 16);
    cnt += __shfl_down(cnt, 1, 16);
    if (m == 0) counts2[(b * NF + f0 + r) * 32 + c0] = cnt;
}

__global__ __launch_bounds__(256) void k_prefix(const int* __restrict__ counts2, int* __restrict__ prefix2) {
    const int b = blockIdx.x;
    const int tid = threadIdx.x;  // tid == freq row
    const int* cb = counts2 + b * NF * 32;
    int* pb = prefix2 + b * NF * 32;
    int local[32];
    int s = 0;
    for (int c = 0; c < 32; c++) {
        local[c] = cb[tid * 32 + c];
        s += local[c];
    }
    __shared__ int tot[256];
    tot[tid] = s;
    __syncthreads();
    for (int off = 1; off < 256; off <<= 1) {
        int v = (tid >= off) ? tot[tid - off] : 0;
        __syncthreads();
        tot[tid] += v;
        __syncthreads();
    }
    int run = tot[tid] - s;
    for (int c = 0; c < 32; c++) {
        pb[tid * 32 + c] = run;
        run += local[c];
    }
}

__global__ __launch_bounds__(256, 4) void k_extract(const float* __restrict__ spec, unsigned* __restrict__ mm,
                                                    const int* __restrict__ prefix2, float* __restrict__ out) {
    const int b = blockIdx.z;
    const int f0 = blockIdx.y * TF;
    const int t0 = blockIdx.x * TT;
    const int c0 = blockIdx.x;
    // prefix is monotone in row-major (f,chunk) order; tile min is at (f0,c0)
    if (prefix2[(b * NF + f0) * 32 + c0] >= PAD_LEN) return;

    const int tid = threadIdx.x;
    __shared__ __align__(16) float sR1[R1_WORDS];
    __shared__ __align__(16) float sR2[R2_WORDS];
    const float4* sB4 = (const float4*)sR2;

    const float mn = decf(mm[b * 4 + 0]);
    const float mx = decf(mm[b * 4 + 1]);
    const float rinv = 1.0f / (mx - mn);
    const float mn2 = decf(mm[b * 4 + 2]);
    const float mx2 = decf(mm[b * 4 + 3]);
    const float rinv2 = 1.0f / (mx2 - mn2);
    const float* sb_base = spec + (size_t)b * NF * NT;

    const bool interior = (blockIdx.y >= 1 && blockIdx.y <= 14 && blockIdx.x >= 1 && blockIdx.x <= 30);
    if (interior) blur_tile_fast(sb_base, f0, t0, mn, rinv, sR1, sR2, tid);
    else          blur_tile_slow(sb_base, f0, t0, mn, rinv, sR1, sR2, tid);

    const int r = tid >> 4, m = tid & 15;
    const int gf = f0 + r;
    const int base = prefix2[(b * NF + gf) * 32 + c0];
    Win8 w;
    load_win8(sB4, r, m, w);
    bool pos[8];
    int mycnt = 0;
#pragma unroll
    for (int k = 0; k < 8; k++) {
        float x = w.c[k];
        pos[k] = (x >= w.l[k]) && (x >= w.rr[k]) && (x >= w.u[k]) && (x >= w.d[k]) && (x > mn2);
        mycnt += pos[k] ? 1 : 0;
    }
    int scan = mycnt;
    for (int off = 1; off < 16; off <<= 1) {
        int v = __shfl_up(scan, off, 16);
        if (m >= off) scan += v;
    }
    int rank = base + (scan - mycnt);
#pragma unroll
    for (int k = 0; k < 8; k++) {
        if (pos[k]) {
            if (rank < PAD_LEN) {
                int gc = t0 + 8 * m + k;
                out[b * 768 + rank]       = (float)gf * (1.0f / 256.0f);
                out[b * 768 + 256 + rank] = (float)gc * (1.0f / 4096.0f);
                out[b * 768 + 512 + rank] = (w.c[k] - mn2) * rinv2;
            }
            rank++;
        }
    }
}

extern "C" void kernel_launch(void* const* d_in, const int* in_sizes, int n_in,
                              void* d_out, int out_size, void* d_ws, size_t ws_size,
                              hipStream_t stream) {
    const float* spec = (const float*)d_in[0];
    float* out = (float*)d_out;
    unsigned* mm = (unsigned*)((char*)d_ws + MM_OFF);
    int* counts2 = (int*)((char*)d_ws + CNT_OFF);
    int* prefix2 = (int*)((char*)d_ws + PFX_OFF);

    k_init<<<96, 256, 0, stream>>>(out, mm);
    k_minmax<<<dim3(64, NB), 256, 0, stream>>>(spec, mm);
    dim3 tgrid(NT / TT, NF / TF, NB);
    k_main<<<tgrid, 256, 0, stream>>>(spec, mm, counts2);
    k_fallback<<<tgrid, 256, 0, stream>>>(spec, mm, counts2);
    k_prefix<<<NB, 256, 0, stream>>>(counts2, prefix2);
    k_extract<<<tgrid, 256, 0, stream>>>(spec, mm, prefix2, out);
}

// Round 6
// 458.349 us; speedup vs baseline: 1.0343x; 1.0343x over previous
//
#include <hip/hip_runtime.h>

#define NB 32
#define NF 256
#define NT 4096
#define PAD_LEN 256

// f32 gaussian weights: exp(-0.5*c^2)/sum, c=-2..2, sigma=1
#define G0 0.054488684f
#define G1 0.24420134f
#define G2 0.40261995f

#define NEG (-__builtin_inff())

__device__ __forceinline__ unsigned encf(float x) {
    unsigned u = __float_as_uint(x);
    return (u & 0x80000000u) ? ~u : (u | 0x80000000u);
}
__device__ __forceinline__ float decf(unsigned e) {
    unsigned u = (e & 0x80000000u) ? (e ^ 0x80000000u) : ~e;
    return __uint_as_float(u);
}

// ws layout: mm[NB][4] @0 ; counts2[NB][NF][32] @1024 ; prefix2 @1024+1MB
#define MM_OFF 0
#define CNT_OFF 1024
#define PFX_OFF (1024 + NB * NF * 32 * 4)

__global__ __launch_bounds__(256) void k_init(float* __restrict__ out, unsigned* __restrict__ mm) {
    int tid = blockIdx.x * 256 + threadIdx.x;
    if (tid < NB * 3 * PAD_LEN) out[tid] = 0.0f;
    if (tid < NB) {
        mm[tid * 4 + 0] = 0xFFFFFFFFu;
        mm[tid * 4 + 1] = 0u;
        mm[tid * 4 + 2] = 0xFFFFFFFFu;
        mm[tid * 4 + 3] = 0u;
    }
}

__global__ __launch_bounds__(256) void k_minmax(const float* __restrict__ spec, unsigned* __restrict__ mm) {
    const int b = blockIdx.y;
    const float4* q = (const float4*)(spec + (size_t)b * NF * NT) + blockIdx.x * 4096 + threadIdx.x;
    float4 v[16];
#pragma unroll
    for (int u = 0; u < 16; u++) v[u] = q[u * 256];
    float lmin = __builtin_inff(), lmax = -__builtin_inff();
#pragma unroll
    for (int u = 0; u < 16; u++) {
        lmin = fminf(lmin, fminf(fminf(v[u].x, v[u].y), fminf(v[u].z, v[u].w)));
        lmax = fmaxf(lmax, fmaxf(fmaxf(v[u].x, v[u].y), fmaxf(v[u].z, v[u].w)));
    }
    for (int off = 32; off; off >>= 1) {
        lmin = fminf(lmin, __shfl_down(lmin, off));
        lmax = fmaxf(lmax, __shfl_down(lmax, off));
    }
    __shared__ float rmn[4], rmx[4];
    int wave = threadIdx.x >> 6, lane = threadIdx.x & 63;
    if (lane == 0) { rmn[wave] = lmin; rmx[wave] = lmax; }
    __syncthreads();
    if (threadIdx.x == 0) {
        for (int w = 1; w < 4; w++) { lmin = fminf(lmin, rmn[w]); lmax = fmaxf(lmax, rmx[w]); }
        atomicMin(&mm[b * 4 + 0], encf(lmin));
        atomicMax(&mm[b * 4 + 1], encf(lmax));
    }
}

// ============================================================================
// Register-streaming fused pipeline. Each lane owns 8 output columns
// (oc = t0 + 8*lane + [0..8)) and streams 40 spec rows through rolling
// register windows. No LDS in the loop, no barriers, no cross-lane ops
// except the 16-lane count reduce / scan.
//   S[3][24] : spec rows q-2..q, cols rel [-8..15]  (rel to own base)
//   P[5][18] : peak1*(x-mn) rows p-4..p, cols rel [-5..12]  (scale deferred)
//   B[3][10] : blurred rows j-2..j, cols rel [-1..8]
// MODE 0: counts (thr=0) + blur min/max ; MODE 1: recount with thr=mn2
// (guard, normally exits) ; MODE 2: ranked extraction.
// ============================================================================
template <int MODE>
__global__ __launch_bounds__(256, 2) void k_stream(const float* __restrict__ spec,
                                                   unsigned* __restrict__ mm,
                                                   int* __restrict__ counts2,
                                                   const int* __restrict__ prefix2,
                                                   float* __restrict__ out) {
    const int b = blockIdx.z;
    const int bx = blockIdx.x;
    const int wv = threadIdx.x >> 6;
    const int lane = threadIdx.x & 63;
    const int f0 = blockIdx.y * 128 + wv * 32;
    const int t0 = bx * 512;

    float mn2 = 0.0f, rinv2 = 0.0f, thr = 0.0f;
    if (MODE == 1) {
        mn2 = decf(mm[b * 4 + 2]);
        if (mn2 == 0.0f) return;
        thr = mn2;
    }
    if (MODE == 2) {
        // prefix monotone in row-major order; strip min is at (f0, first chunk)
        if (prefix2[(b * NF + f0) * 32 + 4 * bx] >= PAD_LEN) return;
        mn2 = decf(mm[b * 4 + 2]);
        float mx2 = decf(mm[b * 4 + 3]);
        rinv2 = 1.0f / (mx2 - mn2);
        thr = mn2;
    }
    const float mn = decf(mm[b * 4 + 0]);
    const float* sb = spec + (size_t)b * NF * NT;

    const bool eL = (t0 == 0);
    const bool eR = (t0 == NT - 512);
    const bool fTop = (f0 == 0);
    const bool fBot = (f0 == NF - 32);
    const int chunk = 4 * bx + (lane >> 4);

    // per-lane clamped byte offsets for the 6 float4 column groups (row-invariant)
    int cofs[6];
#pragma unroll
    for (int g = 0; g < 6; g++) {
        int c = t0 + 8 * lane - 8 + 4 * g;
        c = c < 0 ? 0 : c;
        c = c > NT - 4 ? NT - 4 : c;
        cofs[g] = c * 4;
    }

    float S[3][24];
    float P[5][18];
    float B[3][10];
    float lmin = __builtin_inff(), lmax = -__builtin_inff();

#define STEP(K)                                                                              \
    do {                                                                                     \
        { /* ---- load S row q = f0-4+K ---- */                                              \
            const bool offT = ((K) < 4) && fTop;                                             \
            const bool offB = ((K) >= 36) && fBot;                                           \
            float* Srow = S[(K) % 3];                                                        \
            if (offT || offB) {                                                              \
                _Pragma("unroll") for (int ci = 0; ci < 24; ci++) Srow[ci] = NEG;            \
            } else {                                                                         \
                const int q = f0 - 4 + (K);                                                  \
                const char* rp = (const char*)(sb + (size_t)q * NT);                         \
                float4 u0 = *(const float4*)(rp + cofs[0]);                                  \
                float4 u1 = *(const float4*)(rp + cofs[1]);                                  \
                float4 u2 = *(const float4*)(rp + cofs[2]);                                  \
                float4 u3 = *(const float4*)(rp + cofs[3]);                                  \
                float4 u4 = *(const float4*)(rp + cofs[4]);                                  \
                float4 u5 = *(const float4*)(rp + cofs[5]);                                  \
                Srow[0] = u0.x; Srow[1] = u0.y; Srow[2] = u0.z; Srow[3] = u0.w;              \
                Srow[4] = u1.x; Srow[5] = u1.y; Srow[6] = u1.z; Srow[7] = u1.w;              \
                Srow[8] = u2.x; Srow[9] = u2.y; Srow[10] = u2.z; Srow[11] = u2.w;            \
                Srow[12] = u3.x; Srow[13] = u3.y; Srow[14] = u3.z; Srow[15] = u3.w;          \
                Srow[16] = u4.x; Srow[17] = u4.y; Srow[18] = u4.z; Srow[19] = u4.w;          \
                Srow[20] = u5.x; Srow[21] = u5.y; Srow[22] = u5.z; Srow[23] = u5.w;          \
                if (eL) { if (lane == 0) {                                                   \
                    _Pragma("unroll") for (int ci = 0; ci < 8; ci++) Srow[ci] = NEG; } }     \
                if (eR) { if (lane == 63) {                                                  \
                    _Pragma("unroll") for (int ci = 16; ci < 24; ci++) Srow[ci] = NEG; } }   \
            }                                                                                \
        }                                                                                    \
        if ((K) >= 2) { /* ---- P row p = f0+K-5 ---- */                                     \
            const bool skipP = (((K) < 5) && fTop) || (((K) > 36) && fBot);                  \
            if (!skipP) {                                                                    \
                const float* Sm = S[((K) + 1) % 3];                                          \
                const float* Sc = S[((K) + 2) % 3];                                          \
                const float* Sp = S[(K) % 3];                                                \
                float* Pr = P[(K) % 5];                                                      \
                _Pragma("unroll") for (int ci = 0; ci < 18; ci++) {                          \
                    float x = Sc[ci + 3];                                                    \
                    float m = fmaxf(fmaxf(Sc[ci + 2], Sc[ci + 4]),                           \
                                    fmaxf(Sm[ci + 3], Sp[ci + 3]));                          \
                    Pr[ci] = (x >= m) ? (x - mn) : 0.0f;                                     \
                }                                                                            \
                if (eL) { if (lane == 0) {                                                   \
                    Pr[0] = 0.0f; Pr[1] = 0.0f; Pr[2] = 0.0f; Pr[3] = 0.0f; Pr[4] = 0.0f; } }\
                if (eR) { if (lane == 63) {                                                  \
                    Pr[13] = 0.0f; Pr[14] = 0.0f; Pr[15] = 0.0f; Pr[16] = 0.0f;              \
                    Pr[17] = 0.0f; } }                                                       \
            }                                                                                \
        }                                                                                    \
        if ((K) >= 6) { /* ---- V + B row j = f0+K-7 ---- */                                 \
            float* Br = B[(K) % 3];                                                          \
            const bool niB = (((K) == 6) && fTop) || (((K) == 39) && fBot);                  \
            if (niB) {                                                                       \
                _Pragma("unroll") for (int vi = 0; vi < 10; vi++) Br[vi] = NEG;              \
            } else {                                                                         \
                float V[14];                                                                 \
                const float* Pa = P[((K) + 1) % 5];                                          \
                const float* Pb = P[((K) + 2) % 5];                                          \
                const float* Pc = P[((K) + 3) % 5];                                          \
                const float* Pd = P[((K) + 4) % 5];                                          \
                const float* Pe = P[(K) % 5];                                                \
                if (((K) == 7) && fTop) {                                                    \
                    _Pragma("unroll") for (int ci = 0; ci < 14; ci++)                        \
                        V[ci] = G2 * P[0][ci + 2] + (2.0f * G1) * P[1][ci + 2] +             \
                                (2.0f * G0) * P[2][ci + 2];                                  \
                } else if (((K) == 8) && fTop) {                                             \
                    _Pragma("unroll") for (int ci = 0; ci < 14; ci++)                        \
                        V[ci] = G1 * P[0][ci + 2] + (G0 + G2) * P[1][ci + 2] +               \
                                G1 * P[2][ci + 2] + G0 * P[3][ci + 2];                       \
                } else if (((K) == 37) && fBot) {                                            \
                    _Pragma("unroll") for (int ci = 0; ci < 14; ci++)                        \
                        V[ci] = G0 * P[3][ci + 2] + G1 * P[4][ci + 2] +                      \
                                (G2 + G0) * P[0][ci + 2] + G1 * P[1][ci + 2];                \
                } else if (((K) == 38) && fBot) {                                            \
                    _Pragma("unroll") for (int ci = 0; ci < 14; ci++)                        \
                        V[ci] = (2.0f * G0) * P[4][ci + 2] + (2.0f * G1) * P[0][ci + 2] +    \
                                G2 * P[1][ci + 2];                                           \
                } else {                                                                     \
                    _Pragma("unroll") for (int ci = 0; ci < 14; ci++)                        \
                        V[ci] = G0 * (Pa[ci + 2] + Pe[ci + 2]) +                             \
                                G1 * (Pb[ci + 2] + Pd[ci + 2]) + G2 * Pc[ci + 2];            \
                }                                                                            \
                _Pragma("unroll") for (int vi = 0; vi < 10; vi++)                            \
                    Br[vi] = G0 * (V[vi] + V[vi + 4]) + G1 * (V[vi + 1] + V[vi + 3]) +       \
                             G2 * V[vi + 2];                                                 \
                if (eL) { if (lane == 0) {                                                   \
                    Br[0] = NEG;                                                             \
                    Br[1] = G2 * V[3] + (2.0f * G1) * V[4] + (2.0f * G0) * V[5];             \
                    Br[2] = G1 * V[3] + (G0 + G2) * V[4] + G1 * V[5] + G0 * V[6]; } }        \
                if (eR) { if (lane == 63) {                                                  \
                    Br[7] = G0 * V[7] + G1 * V[8] + (G2 + G0) * V[9] + G1 * V[10];           \
                    Br[8] = (2.0f * G0) * V[8] + (2.0f * G1) * V[9] + G2 * V[10];            \
                    Br[9] = NEG; } }                                                         \
            }                                                                                \
        }                                                                                    \
        if ((K) >= 8) { /* ---- peak2 row r = f0+K-8 ---- */                                 \
            const int r = f0 + (K) - 8;                                                      \
            const float* Bm = B[((K) + 1) % 3];                                              \
            const float* Bc = B[((K) + 2) % 3];                                              \
            const float* Bp = B[(K) % 3];                                                    \
            if (MODE == 2) {                                                                 \
                int mycnt = 0; unsigned pbits = 0u; float xv[8];                             \
                _Pragma("unroll") for (int oc = 0; oc < 8; oc++) {                           \
                    float x = Bc[oc + 1];                                                    \
                    float m = fmaxf(fmaxf(Bc[oc], Bc[oc + 2]),                               \
                                    fmaxf(Bm[oc + 1], Bp[oc + 1]));                          \
                    bool p = (x >= m) && (x > thr);                                          \
                    pbits |= (p ? (1u << oc) : 0u);                                          \
                    mycnt += p ? 1 : 0;                                                      \
                    xv[oc] = x;                                                              \
                }                                                                            \
                int scan = mycnt;                                                            \
                { int v_ = __shfl_up(scan, 1, 16); if ((lane & 15) >= 1) scan += v_; }       \
                { int v_ = __shfl_up(scan, 2, 16); if ((lane & 15) >= 2) scan += v_; }       \
                { int v_ = __shfl_up(scan, 4, 16); if ((lane & 15) >= 4) scan += v_; }       \
                { int v_ = __shfl_up(scan, 8, 16); if ((lane & 15) >= 8) scan += v_; }       \
                const int base = prefix2[(b * NF + r) * 32 + chunk];                         \
                int rank = base + scan - mycnt;                                              \
                _Pragma("unroll") for (int oc = 0; oc < 8; oc++) {                           \
                    if ((pbits >> oc) & 1u) {                                                \
                        if (rank < PAD_LEN) {                                                \
                            out[b * 768 + rank] = (float)r * (1.0f / 256.0f);                \
                            out[b * 768 + 256 + rank] =                                      \
                                (float)(t0 + 8 * lane + oc) * (1.0f / 4096.0f);              \
                            out[b * 768 + 512 + rank] = (xv[oc] - mn2) * rinv2;              \
                        }                                                                    \
                        rank++;                                                              \
                    }                                                                        \
                }                                                                            \
            } else {                                                                         \
                int cnt = 0;                                                                 \
                _Pragma("unroll") for (int oc = 0; oc < 8; oc++) {                           \
                    float x = Bc[oc + 1];                                                    \
                    float m = fmaxf(fmaxf(Bc[oc], Bc[oc + 2]),                               \
                                    fmaxf(Bm[oc + 1], Bp[oc + 1]));                          \
                    if (MODE == 0) { lmin = fminf(lmin, x); lmax = fmaxf(lmax, x); }         \
                    cnt += ((x >= m) && (x > thr)) ? 1 : 0;                                  \
                }                                                                            \
                cnt += __shfl_down(cnt, 8, 16);                                              \
                cnt += __shfl_down(cnt, 4, 16);                                              \
                cnt += __shfl_down(cnt, 2, 16);                                              \
                cnt += __shfl_down(cnt, 1, 16);                                              \
                if ((lane & 15) == 0) counts2[(b * NF + r) * 32 + chunk] = cnt;              \
            }                                                                                \
        }                                                                                    \
    } while (0)

    STEP(0);  STEP(1);  STEP(2);  STEP(3);  STEP(4);  STEP(5);  STEP(6);  STEP(7);
    STEP(8);  STEP(9);  STEP(10); STEP(11); STEP(12); STEP(13); STEP(14); STEP(15);
    STEP(16); STEP(17); STEP(18); STEP(19); STEP(20); STEP(21); STEP(22); STEP(23);
    STEP(24); STEP(25); STEP(26); STEP(27); STEP(28); STEP(29); STEP(30); STEP(31);
    STEP(32); STEP(33); STEP(34); STEP(35); STEP(36); STEP(37); STEP(38); STEP(39);
#undef STEP

    if (MODE == 0) {
        for (int off = 32; off; off >>= 1) {
            lmin = fminf(lmin, __shfl_down(lmin, off));
            lmax = fmaxf(lmax, __shfl_down(lmax, off));
        }
        __shared__ float red[8];
        if (lane == 0) { red[wv] = lmin; red[4 + wv] = lmax; }
        __syncthreads();
        if (threadIdx.x == 0) {
            for (int w = 1; w < 4; w++) {
                lmin = fminf(lmin, red[w]);
                lmax = fmaxf(lmax, red[4 + w]);
            }
            atomicMin(&mm[b * 4 + 2], encf(lmin));
            atomicMax(&mm[b * 4 + 3], encf(lmax));
        }
    }
}

__global__ __launch_bounds__(256) void k_prefix(const int* __restrict__ counts2, int* __restrict__ prefix2) {
    const int b = blockIdx.x;
    const int tid = threadIdx.x;  // tid == freq row
    const int* cb = counts2 + b * NF * 32;
    int* pb = prefix2 + b * NF * 32;
    int local[32];
    int s = 0;
    for (int c = 0; c < 32; c++) {
        local[c] = cb[tid * 32 + c];
        s += local[c];
    }
    __shared__ int tot[256];
    tot[tid] = s;
    __syncthreads();
    for (int off = 1; off < 256; off <<= 1) {
        int v = (tid >= off) ? tot[tid - off] : 0;
        __syncthreads();
        tot[tid] += v;
        __syncthreads();
    }
    int run = tot[tid] - s;
    for (int c = 0; c < 32; c++) {
        pb[tid * 32 + c] = run;
        run += local[c];
    }
}

extern "C" void kernel_launch(void* const* d_in, const int* in_sizes, int n_in,
                              void* d_out, int out_size, void* d_ws, size_t ws_size,
                              hipStream_t stream) {
    const float* spec = (const float*)d_in[0];
    float* out = (float*)d_out;
    unsigned* mm = (unsigned*)((char*)d_ws + MM_OFF);
    int* counts2 = (int*)((char*)d_ws + CNT_OFF);
    int* prefix2 = (int*)((char*)d_ws + PFX_OFF);

    k_init<<<96, 256, 0, stream>>>(out, mm);
    k_minmax<<<dim3(64, NB), 256, 0, stream>>>(spec, mm);
    dim3 sgrid(NT / 512, NF / 128, NB);
    k_stream<0><<<sgrid, 256, 0, stream>>>(spec, mm, counts2, nullptr, nullptr);
    k_stream<1><<<sgrid, 256, 0, stream>>>(spec, mm, counts2, nullptr, nullptr);
    k_prefix<<<NB, 256, 0, stream>>>(counts2, prefix2);
    k_stream<2><<<sgrid, 256, 0, stream>>>(spec, mm, counts2, prefix2, out);
}